// Round 10
// baseline (556.213 us; speedup 1.0000x reference)
//
#include <hip/hip_runtime.h>
#include <stdint.h>

#define DEV __device__ __forceinline__

using f32x4  = __attribute__((ext_vector_type(4))) float;
using bf16x8 = __attribute__((ext_vector_type(8))) __bf16;
using bf16x4 = __attribute__((ext_vector_type(4))) __bf16;

static constexpr int SEQ  = 2048;
static constexpr int FEA  = 1024;
static constexpr int NHEAD = 16;
static constexpr int MROWS = 4096;  // B*S
// scale folded into Wq: (1/sqrt(64)) * log2(e)  -> scores directly in exp2 domain
static constexpr float QK_SCALE = 0.18033688011112042f;

// DIAGNOSTIC ROUND: attn body repeated 3x inside one dispatch (idempotent)
// to lift it above the ~330us harness fills into the top-5 counter rows.
static constexpr int REPS = 3;

DEV f32x4 mfma16(bf16x8 a, bf16x8 b, f32x4 c) {
  return __builtin_amdgcn_mfma_f32_16x16x32_bf16(a, b, c, 0, 0, 0);
}

DEV void gload16(const void* g, void* l) {
  __builtin_amdgcn_global_load_lds((__attribute__((address_space(1))) void*)g,
                                   (__attribute__((address_space(3))) void*)l,
                                   16, 0, 0);
}

#define FENCE_VMCNT(n) asm volatile("s_waitcnt vmcnt(" #n ")" ::: "memory")
#define FENCE_LGKM0()  asm volatile("s_waitcnt lgkmcnt(0)" ::: "memory")

// ---------------------------------------------------------------- convert ---
struct ConvSeg { const float* src; __bf16* dst; int n4; float scale; };
struct ConvArgs { ConvSeg seg[7]; };

__global__ __launch_bounds__(256) void convert_k(ConvArgs a) {
  const ConvSeg sg = a.seg[blockIdx.y];
  const int stride = gridDim.x * blockDim.x;
  for (int i = blockIdx.x * blockDim.x + threadIdx.x; i < sg.n4; i += stride) {
    const f32x4 v = *(const f32x4*)(sg.src + (size_t)i * 4);
    bf16x4 o = {(__bf16)(v[0] * sg.scale), (__bf16)(v[1] * sg.scale),
                (__bf16)(v[2] * sg.scale), (__bf16)(v[3] * sg.scale)};
    *(bf16x4*)(sg.dst + (size_t)i * 4) = o;
  }
}

// ------------------------------------------------------------------- GEMM ---
DEV void gemm_core64(const __bf16* __restrict__ A, const __bf16* __restrict__ Bt,
                     char* lds, int row0, int col0, int tid, f32x4 (&acc)[4][4]) {
  char* Alds = lds;
  char* Blds = lds + 16384;
  constexpr int K = 1024;
  const int lane = tid & 63;
  const int w    = tid >> 6;
  const int ci   = lane & 15;
  const int g    = lane >> 4;
  const int wr   = w >> 1, wc = w & 1;

  const __bf16* gA[4]; const __bf16* gB[4];
  char* lA[4]; char* lB[4];
#pragma unroll
  for (int j = 0; j < 4; ++j) {
    const int c = tid + 256 * j;
    const int r = c >> 3, s = c & 7;
    const int gsw = (s ^ (r & 7)) * 8;     // pre-swizzled source column
    gA[j] = A  + (size_t)(row0 + r) * K + gsw;
    gB[j] = Bt + (size_t)(col0 + r) * K + gsw;
    lA[j] = Alds + c * 16;
    lB[j] = Blds + c * 16;
  }
  const int rsw = (ci & 7) << 4;

  for (int k0 = 0; k0 < K; k0 += 64) {
    __syncthreads();
#pragma unroll
    for (int j = 0; j < 4; ++j) {
      gload16(gA[j] + k0, lA[j]);
      gload16(gB[j] + k0, lB[j]);
    }
    __syncthreads();
#pragma unroll
    for (int kk = 0; kk < 2; ++kk) {
      bf16x8 af[4], bfr[4];
#pragma unroll
      for (int m = 0; m < 4; ++m)
        af[m] = *(const bf16x8*)(Alds + (wr * 64 + m * 16 + ci) * 128 +
                                 ((kk * 64 + g * 16) ^ rsw));
#pragma unroll
      for (int n = 0; n < 4; ++n)
        bfr[n] = *(const bf16x8*)(Blds + (wc * 64 + n * 16 + ci) * 128 +
                                  ((kk * 64 + g * 16) ^ rsw));
#pragma unroll
      for (int m = 0; m < 4; ++m)
#pragma unroll
        for (int n = 0; n < 4; ++n)
          acc[m][n] = mfma16(af[m], bfr[n], acc[m][n]);
    }
  }
}

struct QkvArgs {
  const __bf16* A[3];
  const __bf16* Bt[3];
  const float*  bias[3];
  float         bscale[3];
  __bf16*       out[3];
};

__global__ __launch_bounds__(256) void gemm_qkv(QkvArgs args) {
  __shared__ __align__(16) char lds[32768];
  const int z = blockIdx.z;
  const int tid = threadIdx.x;
  const int row0 = blockIdx.x * 128;
  const int col0 = blockIdx.y * 128;
  f32x4 acc[4][4] = {};
  gemm_core64(args.A[z], args.Bt[z], lds, row0, col0, tid, acc);

  const int lane = tid & 63;
  const int ci = lane & 15, g = lane >> 4;
  const int w = tid >> 6;
  const int wr = w >> 1, wc = w & 1;
  const float* bias = args.bias[z];
  const float bscale = args.bscale[z];
  __bf16* outp = args.out[z];
  const bool vt = (z == 2);
#pragma unroll
  for (int m = 0; m < 4; ++m)
#pragma unroll
    for (int n = 0; n < 4; ++n)
#pragma unroll
      for (int r = 0; r < 4; ++r) {
        const int gr = row0 + wr * 64 + m * 16 + 4 * g + r;
        const int gc = col0 + wc * 64 + n * 16 + ci;
        const float vv = acc[m][n][r] + bias[gc] * bscale;
        const int b = gr >> 11, s = gr & (SEQ - 1);
        const int h = gc >> 6,  d = gc & 63;
        if (!vt)
          outp[(((size_t)b * NHEAD + h) * SEQ + s) * 64 + d] = (__bf16)vv;
        else
          outp[(((size_t)b * NHEAD + h) * 64 + d) * SEQ + s] = (__bf16)vv;
      }
}

__global__ __launch_bounds__(256) void gemm_fc(const __bf16* __restrict__ A,
                                               const __bf16* __restrict__ Bt,
                                               const float* __restrict__ bias,
                                               float* __restrict__ outp) {
  __shared__ __align__(16) char lds[32768];
  const int tid = threadIdx.x;
  const int row0 = blockIdx.x * 128;
  const int col0 = blockIdx.y * 128;
  f32x4 acc[4][4] = {};
  gemm_core64(A, Bt, lds, row0, col0, tid, acc);

  const int lane = tid & 63;
  const int ci = lane & 15, g = lane >> 4;
  const int w = tid >> 6;
  const int wr = w >> 1, wc = w & 1;
#pragma unroll
  for (int m = 0; m < 4; ++m)
#pragma unroll
    for (int n = 0; n < 4; ++n)
#pragma unroll
      for (int r = 0; r < 4; ++r) {
        const int gr = row0 + wr * 64 + m * 16 + 4 * g + r;
        const int gc = col0 + wc * 64 + n * 16 + ci;
        const float vv = fmaxf(acc[m][n][r] + bias[gc], 0.0f);
        __builtin_nontemporal_store(vv, &outp[(size_t)gr * FEA + gc]);
      }
}

// -------------------------------------------------------------- attention ---
// R9 structure, body repeated REPS times inside one dispatch for profiling.
static constexpr int QBLK = 32;
static constexpr int GQT  = 4;           // q-tiles per block
static constexpr int KVB  = 128;
static constexpr int NT   = SEQ / KVB;   // 16

__global__ __launch_bounds__(512, 4) void attn_fused(const __bf16* __restrict__ Qh,
                                                     const __bf16* __restrict__ Kh,
                                                     const __bf16* __restrict__ VhT,
                                                     float* __restrict__ attn_out,
                                                     __bf16* __restrict__ Cbuf) {
  __shared__ __align__(16) char smem[65536];
  __shared__ float rs_lds[8][16];
  __shared__ float linv_lds[QBLK];
  float* pvf = (float*)(smem + 32768);

  const int tid  = threadIdx.x;
  const int lane = tid & 63;
  const int w    = tid >> 6;
  const int ci   = lane & 15;
  const int g    = lane >> 4;
  const int qg   = w >> 2;
  const int kg   = w & 3;

  const int id   = blockIdx.x;           // 512 blocks
  const int xcd  = id & 7;
  const int idx  = id >> 3;              // 0..63
  const int bh   = xcd * 4 + (idx >> 4);
  const int qgrp = idx & 15;

  const __bf16* Qbase = Qh + ((size_t)bh * SEQ + (size_t)qgrp * (QBLK * GQT)) * 64;
  const char*   Kbyt  = (const char*)(Kh  + (size_t)bh * SEQ * 64);
  const char*   Vbyt  = (const char*)(VhT + (size_t)bh * 64 * SEQ);

  const int cA = tid, cB = tid + 512;
  const int kgoffA = ((cA >> 3) * 128) + (((cA & 7) ^ ((cA >> 3) & 7)) * 16);
  const int kgoffB = ((cB >> 3) * 128) + (((cB & 7) ^ ((cB >> 3) & 7)) * 16);
  const int vdA = cA >> 4, vdB = cB >> 4;
  const int vgoffA = vdA * (SEQ * 2) + (((cA & 15) ^ (vdA & 7)) * 16);
  const int vgoffB = vdB * (SEQ * 2) + (((cB & 15) ^ (vdB & 7)) * 16);

#define STAGE_K(t, boff) { gload16(Kbyt + (size_t)(t) * 16384 + kgoffA, smem + (boff) + cA * 16); \
                           gload16(Kbyt + (size_t)(t) * 16384 + kgoffB, smem + (boff) + cB * 16); }
#define STAGE_V(t, boff) { gload16(Vbyt + (size_t)(t) * 256 + vgoffA, smem + 16384 + (boff) + cA * 16); \
                           gload16(Vbyt + (size_t)(t) * 256 + vgoffB, smem + 16384 + (boff) + cB * 16); }

  const int kswz  = (ci & 7) << 4;
  const int krow0 = kg * 4096 + ci * 128;

  for (int rep = 0; rep < REPS; ++rep) {
    // current q-tile fragments (tile 0)
    bf16x8 cq0, cq1;
    {
      const __bf16* qp = Qbase + (qg * 16 + ci) * 64;
      cq0 = *(const bf16x8*)(qp + 8 * g);
      cq1 = *(const bf16x8*)(qp + 32 + 8 * g);
    }

    // ---- prologue: rowsums for q-tile 0 ----
    float rs = 0.f;
    STAGE_K(0, 0);
    STAGE_K(1, 16384);
    for (int p = 0; p < NT / 2; ++p) {
      const int base = (p & 1) << 15;
      __builtin_amdgcn_s_barrier();
      if (p < NT / 2 - 1) {
        STAGE_K(2 * p + 2, base ^ 32768);
        STAGE_K(2 * p + 3, (base ^ 32768) + 16384);
        FENCE_VMCNT(4);
      } else {
        FENCE_VMCNT(0);
      }
#pragma unroll
      for (int hb = 0; hb < 2; ++hb) {
        const char* kt = smem + base + hb * 16384 + krow0;
#pragma unroll
        for (int s = 0; s < 2; ++s) {
          const bf16x8 k0 = *(const bf16x8*)(kt + s * 2048 + ((16 * g) ^ kswz));
          const bf16x8 k1 = *(const bf16x8*)(kt + s * 2048 + ((64 + 16 * g) ^ kswz));
          f32x4 sf = {0.f, 0.f, 0.f, 0.f};
          sf = mfma16(k0, cq0, sf);
          sf = mfma16(k1, cq1, sf);
#pragma unroll
          for (int r = 0; r < 4; ++r) rs += __builtin_amdgcn_exp2f(sf[r]);
        }
      }
      FENCE_LGKM0();
    }
    rs += __shfl_xor(rs, 16);
    rs += __shfl_xor(rs, 32);
    if (lane < 16) rs_lds[w][lane] = rs;
    __syncthreads();
    if (tid < QBLK) {
      const int qg2 = tid >> 4;
      float ts = 0.f;
#pragma unroll
      for (int kk = 0; kk < 4; ++kk) ts += rs_lds[qg2 * 4 + kk][tid & 15];
      linv_lds[tid] = -__log2f(ts);
    }
    __syncthreads();

    // ---- main: merged pass2(i) + pass1(i+1) ----
    for (int i = 0; i < GQT; ++i) {
      const bool more = (i + 1 < GQT);
      bf16x8 nq0 = {}, nq1 = {};
      if (more) {
        const __bf16* qp = Qbase + ((i + 1) * QBLK + qg * 16 + ci) * 64;
        nq0 = *(const bf16x8*)(qp + 8 * g);
        nq1 = *(const bf16x8*)(qp + 32 + 8 * g);
      }
      const float linv = linv_lds[qg * 16 + ci];
      float* orow = attn_out + ((size_t)bh * SEQ + (size_t)(qgrp * GQT + i) * QBLK +
                                qg * 16 + ci) * SEQ + kg * 32 + 4 * g;
      f32x4 apv[4] = {};
      float nrs = 0.f;

      STAGE_K(0, 0);
      STAGE_V(0, 0);
      for (int t = 0; t < NT; ++t) {
        const int coff = (t & 1) << 15;
        __builtin_amdgcn_s_barrier();
        if (t < NT - 1) {
          STAGE_K(t + 1, coff ^ 32768);
          STAGE_V(t + 1, coff ^ 32768);
          if (t == 0) FENCE_VMCNT(4);
          else        FENCE_VMCNT(6);
        } else {
          FENCE_VMCNT(2);
        }

        f32x4 e[2];
#pragma unroll
        for (int s = 0; s < 2; ++s) {
          const char* kt = smem + coff + krow0 + s * 2048;
          const bf16x8 k0 = *(const bf16x8*)(kt + ((16 * g) ^ kswz));
          const bf16x8 k1 = *(const bf16x8*)(kt + ((64 + 16 * g) ^ kswz));
          f32x4 sf = {0.f, 0.f, 0.f, 0.f};
          sf = mfma16(k0, cq0, sf);
          sf = mfma16(k1, cq1, sf);
          if (more) {
            f32x4 nsf = {0.f, 0.f, 0.f, 0.f};
            nsf = mfma16(k0, nq0, nsf);
            nsf = mfma16(k1, nq1, nsf);
#pragma unroll
            for (int r = 0; r < 4; ++r) nrs += __builtin_amdgcn_exp2f(nsf[r]);
          }
#pragma unroll
          for (int r = 0; r < 4; ++r) e[s][r] = __builtin_amdgcn_exp2f(sf[r] + linv);
          __builtin_nontemporal_store(e[s], (f32x4*)(orow + t * 128 + s * 16));
        }
        const bf16x8 pa = {(__bf16)e[0][0], (__bf16)e[0][1], (__bf16)e[0][2], (__bf16)e[0][3],
                           (__bf16)e[1][0], (__bf16)e[1][1], (__bf16)e[1][2], (__bf16)e[1][3]};
        const int inr0 = (64 * kg + 8 * g) ^ kswz;
        const int inr1 = (64 * kg + 32 + 8 * g) ^ kswz;
#pragma unroll
        for (int dt = 0; dt < 4; ++dt) {
          const char* vrow = smem + 16384 + coff + (dt * 16 + ci) * 256;
          const bf16x4 v0 = *(const bf16x4*)(vrow + inr0);
          const bf16x4 v1 = *(const bf16x4*)(vrow + inr1);
          const bf16x8 vb = {v0[0], v0[1], v0[2], v0[3], v1[0], v1[1], v1[2], v1[3]};
          apv[dt] = mfma16(pa, vb, apv[dt]);
        }
        FENCE_LGKM0();
      }

      // ---- transition: Cb write for tile i, linv for tile i+1 ----
      __syncthreads();
      {
        const int basew = (qg * 4 + kg) * 16;
#pragma unroll
        for (int dt = 0; dt < 4; ++dt)
#pragma unroll
          for (int r = 0; r < 4; ++r)
            pvf[(basew + 4 * g + r) * 64 + dt * 16 + ci] = apv[dt][r];
      }
      if (more) {
        nrs += __shfl_xor(nrs, 16);
        nrs += __shfl_xor(nrs, 32);
        if (lane < 16) rs_lds[w][lane] = nrs;
      }
      __syncthreads();
      {
        const int qq  = tid >> 4;
        const int d0  = (tid & 15) * 4;
        const int qg2 = qq >> 4, row = qq & 15;
        f32x4 ss = {0.f, 0.f, 0.f, 0.f};
#pragma unroll
        for (int kk = 0; kk < 4; ++kk)
          ss += *(const f32x4*)&pvf[((qg2 * 4 + kk) * 16 + row) * 64 + d0];
        const int b = bh >> 4, h = bh & 15;
        const int srow = (qgrp * GQT + i) * QBLK + qq;
        const bf16x4 o = {(__bf16)ss[0], (__bf16)ss[1], (__bf16)ss[2], (__bf16)ss[3]};
        *(bf16x4*)&Cbuf[((size_t)b * SEQ + srow) * FEA + h * 64 + d0] = o;
      }
      if (more && tid < QBLK) {
        const int qg2 = tid >> 4;
        float ts = 0.f;
#pragma unroll
        for (int kk = 0; kk < 4; ++kk) ts += rs_lds[qg2 * 4 + kk][tid & 15];
        linv_lds[tid] = -__log2f(ts);
      }
      cq0 = nq0; cq1 = nq1;
      FENCE_LGKM0();
      __syncthreads();
    }
  }  // rep
#undef STAGE_K
#undef STAGE_V
}

// ------------------------------------------------------------------ launch ---
extern "C" void kernel_launch(void* const* d_in, const int* in_sizes, int n_in,
                              void* d_out, int out_size, void* d_ws, size_t ws_size,
                              hipStream_t stream) {
  const float* q    = (const float*)d_in[0];
  const float* k    = (const float*)d_in[1];
  const float* v    = (const float*)d_in[2];
  const float* wq_w = (const float*)d_in[3];
  const float* wq_b = (const float*)d_in[4];
  const float* wk_w = (const float*)d_in[5];
  const float* wk_b = (const float*)d_in[6];
  const float* wv_w = (const float*)d_in[7];
  const float* wv_b = (const float*)d_in[8];
  const float* fc_w = (const float*)d_in[9];
  const float* fc_b = (const float*)d_in[10];

  float* out0 = (float*)d_out;
  float* attn = out0 + (size_t)MROWS * FEA;  // second tuple output

  // bf16 scratch that dies before attn runs -> reuse the attn output region
  __bf16* Xq = (__bf16*)attn;
  __bf16* Xk = Xq + (size_t)MROWS * FEA;
  __bf16* Xv = Xk + (size_t)MROWS * FEA;
  __bf16* Wq = Xv + (size_t)MROWS * FEA;
  __bf16* Wk = Wq + (size_t)FEA * FEA;
  __bf16* Wv = Wk + (size_t)FEA * FEA;

  // persistent scratch (lives across attn) -> d_ws, 34 MiB
  __bf16* Qh  = (__bf16*)d_ws;
  __bf16* Kh  = Qh  + (size_t)MROWS * FEA;
  __bf16* VhT = Kh  + (size_t)MROWS * FEA;
  __bf16* Cb  = VhT + (size_t)MROWS * FEA;
  __bf16* Wfc = Cb  + (size_t)MROWS * FEA;

  ConvArgs ca;
  ca.seg[0] = {q,    Xq,  (MROWS * FEA) / 4, 1.0f};
  ca.seg[1] = {k,    Xk,  (MROWS * FEA) / 4, 1.0f};
  ca.seg[2] = {v,    Xv,  (MROWS * FEA) / 4, 1.0f};
  ca.seg[3] = {wq_w, Wq,  (FEA * FEA) / 4,   QK_SCALE};
  ca.seg[4] = {wk_w, Wk,  (FEA * FEA) / 4,   1.0f};
  ca.seg[5] = {wv_w, Wv,  (FEA * FEA) / 4,   1.0f};
  ca.seg[6] = {fc_w, Wfc, (FEA * FEA) / 4,   1.0f};
  convert_k<<<dim3(512, 7), 256, 0, stream>>>(ca);

  QkvArgs qa;
  qa.A[0] = Xq; qa.Bt[0] = Wq; qa.bias[0] = wq_b; qa.bscale[0] = QK_SCALE; qa.out[0] = Qh;
  qa.A[1] = Xk; qa.Bt[1] = Wk; qa.bias[1] = wk_b; qa.bscale[1] = 1.0f;     qa.out[1] = Kh;
  qa.A[2] = Xv; qa.Bt[2] = Wv; qa.bias[2] = wv_b; qa.bscale[2] = 1.0f;     qa.out[2] = VhT;
  gemm_qkv<<<dim3(MROWS / 128, FEA / 128, 3), 256, 0, stream>>>(qa);

  attn_fused<<<dim3(512), 512, 0, stream>>>(Qh, Kh, VhT, attn, Cb);

  gemm_fc<<<dim3(MROWS / 128, FEA / 128), 256, 0, stream>>>(Cb, Wfc, fc_b, out0);
}

// Round 12
// 239.884 us; speedup vs baseline: 2.3187x; 2.3187x over previous
//
#include <hip/hip_runtime.h>
#include <stdint.h>

#define DEV __device__ __forceinline__

using f32x4  = __attribute__((ext_vector_type(4))) float;
using bf16x8 = __attribute__((ext_vector_type(8))) __bf16;
using bf16x4 = __attribute__((ext_vector_type(4))) __bf16;

static constexpr int SEQ  = 2048;
static constexpr int FEA  = 1024;
static constexpr int NHEAD = 16;
static constexpr int MROWS = 4096;  // B*S
// scale folded into Wq: (1/sqrt(64)) * log2(e)  -> scores directly in exp2 domain
static constexpr float QK_SCALE = 0.18033688011112042f;

DEV f32x4 mfma16(bf16x8 a, bf16x8 b, f32x4 c) {
  return __builtin_amdgcn_mfma_f32_16x16x32_bf16(a, b, c, 0, 0, 0);
}

DEV void gload16(const void* g, void* l) {
  __builtin_amdgcn_global_load_lds((__attribute__((address_space(1))) void*)g,
                                   (__attribute__((address_space(3))) void*)l,
                                   16, 0, 0);
}

#define FENCE_VMCNT(n) asm volatile("s_waitcnt vmcnt(" #n ")" ::: "memory")
#define FENCE_LGKM0()  asm volatile("s_waitcnt lgkmcnt(0)" ::: "memory")

// ---------------------------------------------------------------- convert ---
struct ConvSeg { const float* src; __bf16* dst; int n4; float scale; };
struct ConvArgs { ConvSeg seg[7]; };

__global__ __launch_bounds__(256) void convert_k(ConvArgs a) {
  const ConvSeg sg = a.seg[blockIdx.y];
  const int stride = gridDim.x * blockDim.x;
  for (int i = blockIdx.x * blockDim.x + threadIdx.x; i < sg.n4; i += stride) {
    const f32x4 v = *(const f32x4*)(sg.src + (size_t)i * 4);
    bf16x4 o = {(__bf16)(v[0] * sg.scale), (__bf16)(v[1] * sg.scale),
                (__bf16)(v[2] * sg.scale), (__bf16)(v[3] * sg.scale)};
    *(bf16x4*)(sg.dst + (size_t)i * 4) = o;
  }
}

// ------------------------------------------------------------------- GEMM ---
DEV void gemm_core64(const __bf16* __restrict__ A, const __bf16* __restrict__ Bt,
                     char* lds, int row0, int col0, int tid, f32x4 (&acc)[4][4]) {
  char* Alds = lds;
  char* Blds = lds + 16384;
  constexpr int K = 1024;
  const int lane = tid & 63;
  const int w    = tid >> 6;
  const int ci   = lane & 15;
  const int g    = lane >> 4;
  const int wr   = w >> 1, wc = w & 1;

  const __bf16* gA[4]; const __bf16* gB[4];
  char* lA[4]; char* lB[4];
#pragma unroll
  for (int j = 0; j < 4; ++j) {
    const int c = tid + 256 * j;
    const int r = c >> 3, s = c & 7;
    const int gsw = (s ^ (r & 7)) * 8;     // pre-swizzled source column
    gA[j] = A  + (size_t)(row0 + r) * K + gsw;
    gB[j] = Bt + (size_t)(col0 + r) * K + gsw;
    lA[j] = Alds + c * 16;
    lB[j] = Blds + c * 16;
  }
  const int rsw = (ci & 7) << 4;

  for (int k0 = 0; k0 < K; k0 += 64) {
    __syncthreads();
#pragma unroll
    for (int j = 0; j < 4; ++j) {
      gload16(gA[j] + k0, lA[j]);
      gload16(gB[j] + k0, lB[j]);
    }
    __syncthreads();
#pragma unroll
    for (int kk = 0; kk < 2; ++kk) {
      bf16x8 af[4], bfr[4];
#pragma unroll
      for (int m = 0; m < 4; ++m)
        af[m] = *(const bf16x8*)(Alds + (wr * 64 + m * 16 + ci) * 128 +
                                 ((kk * 64 + g * 16) ^ rsw));
#pragma unroll
      for (int n = 0; n < 4; ++n)
        bfr[n] = *(const bf16x8*)(Blds + (wc * 64 + n * 16 + ci) * 128 +
                                  ((kk * 64 + g * 16) ^ rsw));
#pragma unroll
      for (int m = 0; m < 4; ++m)
#pragma unroll
        for (int n = 0; n < 4; ++n)
          acc[m][n] = mfma16(af[m], bfr[n], acc[m][n]);
    }
  }
}

struct QkvArgs {
  const __bf16* A[3];
  const __bf16* Bt[3];
  const float*  bias[3];
  float         bscale[3];
  __bf16*       out[3];
};

__global__ __launch_bounds__(256) void gemm_qkv(QkvArgs args) {
  __shared__ __align__(16) char lds[32768];
  const int z = blockIdx.z;
  const int tid = threadIdx.x;
  const int row0 = blockIdx.x * 128;
  const int col0 = blockIdx.y * 128;
  f32x4 acc[4][4] = {};
  gemm_core64(args.A[z], args.Bt[z], lds, row0, col0, tid, acc);

  const int lane = tid & 63;
  const int ci = lane & 15, g = lane >> 4;
  const int w = tid >> 6;
  const int wr = w >> 1, wc = w & 1;
  const float* bias = args.bias[z];
  const float bscale = args.bscale[z];
  __bf16* outp = args.out[z];
  const bool vt = (z == 2);
#pragma unroll
  for (int m = 0; m < 4; ++m)
#pragma unroll
    for (int n = 0; n < 4; ++n)
#pragma unroll
      for (int r = 0; r < 4; ++r) {
        const int gr = row0 + wr * 64 + m * 16 + 4 * g + r;
        const int gc = col0 + wc * 64 + n * 16 + ci;
        const float vv = acc[m][n][r] + bias[gc] * bscale;
        const int b = gr >> 11, s = gr & (SEQ - 1);
        const int h = gc >> 6,  d = gc & 63;
        if (!vt)
          outp[(((size_t)b * NHEAD + h) * SEQ + s) * 64 + d] = (__bf16)vv;
        else
          outp[(((size_t)b * NHEAD + h) * 64 + d) * SEQ + s] = (__bf16)vv;
      }
}

__global__ __launch_bounds__(256) void gemm_fc(const __bf16* __restrict__ A,
                                               const __bf16* __restrict__ Bt,
                                               const float* __restrict__ bias,
                                               float* __restrict__ outp) {
  __shared__ __align__(16) char lds[32768];
  const int tid = threadIdx.x;
  const int row0 = blockIdx.x * 128;
  const int col0 = blockIdx.y * 128;
  f32x4 acc[4][4] = {};
  gemm_core64(A, Bt, lds, row0, col0, tid, acc);

  const int lane = tid & 63;
  const int ci = lane & 15, g = lane >> 4;
  const int w = tid >> 6;
  const int wr = w >> 1, wc = w & 1;
#pragma unroll
  for (int m = 0; m < 4; ++m)
#pragma unroll
    for (int n = 0; n < 4; ++n)
#pragma unroll
      for (int r = 0; r < 4; ++r) {
        const int gr = row0 + wr * 64 + m * 16 + 4 * g + r;
        const int gc = col0 + wc * 64 + n * 16 + ci;
        const float vv = fmaxf(acc[m][n][r] + bias[gc], 0.0f);
        outp[(size_t)gr * FEA + gc] = vv;
      }
}

// -------------------------------------------------------------- attention ---
// R9 structure; PLAIN attn stores (L2 merges the 4 kg-waves' 64B segments into
// 128B lines -> kills the 1.33x write amplification measured in R10).
// pvf reduce: stride 68 f32 (2-way bank spread on writes) placed at smem BASE
// (needs 34.8KB -- the 32KB overlay at smem+32768 overflowed in R11 and
// corrupted linv_lds; base placement is race-free: writes after the post-loop
// barrier, reads before the loop-final barrier, next STAGE after that).
static constexpr int QBLK = 32;
static constexpr int GQT  = 4;           // q-tiles per block
static constexpr int KVB  = 128;
static constexpr int NT   = SEQ / KVB;   // 16

__global__ __launch_bounds__(512, 4) void attn_fused(const __bf16* __restrict__ Qh,
                                                     const __bf16* __restrict__ Kh,
                                                     const __bf16* __restrict__ VhT,
                                                     float* __restrict__ attn_out,
                                                     __bf16* __restrict__ Cbuf) {
  __shared__ __align__(16) char smem[65536];
  __shared__ float rs_lds[8][16];
  __shared__ float linv_lds[QBLK];
  float* pvf = (float*)smem;             // 128 x 68 f32 = 34.8KB at base

  const int tid  = threadIdx.x;
  const int lane = tid & 63;
  const int w    = tid >> 6;
  const int ci   = lane & 15;
  const int g    = lane >> 4;
  const int qg   = w >> 2;
  const int kg   = w & 3;

  const int id   = blockIdx.x;           // 512 blocks
  const int xcd  = id & 7;
  const int idx  = id >> 3;              // 0..63
  const int bh   = xcd * 4 + (idx >> 4);
  const int qgrp = idx & 15;

  const __bf16* Qbase = Qh + ((size_t)bh * SEQ + (size_t)qgrp * (QBLK * GQT)) * 64;
  const char*   Kbyt  = (const char*)(Kh  + (size_t)bh * SEQ * 64);
  const char*   Vbyt  = (const char*)(VhT + (size_t)bh * 64 * SEQ);

  const int cA = tid, cB = tid + 512;
  const int kgoffA = ((cA >> 3) * 128) + (((cA & 7) ^ ((cA >> 3) & 7)) * 16);
  const int kgoffB = ((cB >> 3) * 128) + (((cB & 7) ^ ((cB >> 3) & 7)) * 16);
  const int vdA = cA >> 4, vdB = cB >> 4;
  const int vgoffA = vdA * (SEQ * 2) + (((cA & 15) ^ (vdA & 7)) * 16);
  const int vgoffB = vdB * (SEQ * 2) + (((cB & 15) ^ (vdB & 7)) * 16);

#define STAGE_K(t, boff) { gload16(Kbyt + (size_t)(t) * 16384 + kgoffA, smem + (boff) + cA * 16); \
                           gload16(Kbyt + (size_t)(t) * 16384 + kgoffB, smem + (boff) + cB * 16); }
#define STAGE_V(t, boff) { gload16(Vbyt + (size_t)(t) * 256 + vgoffA, smem + 16384 + (boff) + cA * 16); \
                           gload16(Vbyt + (size_t)(t) * 256 + vgoffB, smem + 16384 + (boff) + cB * 16); }

  const int kswz  = (ci & 7) << 4;
  const int krow0 = kg * 4096 + ci * 128;

  // current q-tile fragments (tile 0)
  bf16x8 cq0, cq1;
  {
    const __bf16* qp = Qbase + (qg * 16 + ci) * 64;
    cq0 = *(const bf16x8*)(qp + 8 * g);
    cq1 = *(const bf16x8*)(qp + 32 + 8 * g);
  }

  // ---- prologue: rowsums for q-tile 0 ----
  float rs = 0.f;
  STAGE_K(0, 0);
  STAGE_K(1, 16384);
  for (int p = 0; p < NT / 2; ++p) {
    const int base = (p & 1) << 15;
    __builtin_amdgcn_s_barrier();
    if (p < NT / 2 - 1) {
      STAGE_K(2 * p + 2, base ^ 32768);
      STAGE_K(2 * p + 3, (base ^ 32768) + 16384);
      FENCE_VMCNT(4);
    } else {
      FENCE_VMCNT(0);
    }
#pragma unroll
    for (int hb = 0; hb < 2; ++hb) {
      const char* kt = smem + base + hb * 16384 + krow0;
#pragma unroll
      for (int s = 0; s < 2; ++s) {
        const bf16x8 k0 = *(const bf16x8*)(kt + s * 2048 + ((16 * g) ^ kswz));
        const bf16x8 k1 = *(const bf16x8*)(kt + s * 2048 + ((64 + 16 * g) ^ kswz));
        f32x4 sf = {0.f, 0.f, 0.f, 0.f};
        sf = mfma16(k0, cq0, sf);
        sf = mfma16(k1, cq1, sf);
#pragma unroll
        for (int r = 0; r < 4; ++r) rs += __builtin_amdgcn_exp2f(sf[r]);
      }
    }
    FENCE_LGKM0();
  }
  rs += __shfl_xor(rs, 16);
  rs += __shfl_xor(rs, 32);
  if (lane < 16) rs_lds[w][lane] = rs;
  __syncthreads();
  if (tid < QBLK) {
    const int qg2 = tid >> 4;
    float ts = 0.f;
#pragma unroll
    for (int kk = 0; kk < 4; ++kk) ts += rs_lds[qg2 * 4 + kk][tid & 15];
    linv_lds[tid] = -__log2f(ts);
  }
  __syncthreads();

  // ---- main: merged pass2(i) + pass1(i+1) ----
  for (int i = 0; i < GQT; ++i) {
    const bool more = (i + 1 < GQT);
    bf16x8 nq0 = {}, nq1 = {};
    if (more) {
      const __bf16* qp = Qbase + ((i + 1) * QBLK + qg * 16 + ci) * 64;
      nq0 = *(const bf16x8*)(qp + 8 * g);
      nq1 = *(const bf16x8*)(qp + 32 + 8 * g);
    }
    const float linv = linv_lds[qg * 16 + ci];
    float* orow = attn_out + ((size_t)bh * SEQ + (size_t)(qgrp * GQT + i) * QBLK +
                              qg * 16 + ci) * SEQ + kg * 32 + 4 * g;
    f32x4 apv[4] = {};
    float nrs = 0.f;

    STAGE_K(0, 0);
    STAGE_V(0, 0);
    for (int t = 0; t < NT; ++t) {
      const int coff = (t & 1) << 15;
      __builtin_amdgcn_s_barrier();
      if (t < NT - 1) {
        STAGE_K(t + 1, coff ^ 32768);
        STAGE_V(t + 1, coff ^ 32768);
        if (t == 0) FENCE_VMCNT(4);
        else        FENCE_VMCNT(6);
      } else {
        FENCE_VMCNT(2);
      }

      f32x4 e[2];
#pragma unroll
      for (int s = 0; s < 2; ++s) {
        const char* kt = smem + coff + krow0 + s * 2048;
        const bf16x8 k0 = *(const bf16x8*)(kt + ((16 * g) ^ kswz));
        const bf16x8 k1 = *(const bf16x8*)(kt + ((64 + 16 * g) ^ kswz));
        f32x4 sf = {0.f, 0.f, 0.f, 0.f};
        sf = mfma16(k0, cq0, sf);
        sf = mfma16(k1, cq1, sf);
        if (more) {
          f32x4 nsf = {0.f, 0.f, 0.f, 0.f};
          nsf = mfma16(k0, nq0, nsf);
          nsf = mfma16(k1, nq1, nsf);
#pragma unroll
          for (int r = 0; r < 4; ++r) nrs += __builtin_amdgcn_exp2f(nsf[r]);
        }
#pragma unroll
        for (int r = 0; r < 4; ++r) e[s][r] = __builtin_amdgcn_exp2f(sf[r] + linv);
        *(f32x4*)(orow + t * 128 + s * 16) = e[s];   // plain store: L2 merges lines
      }
      const bf16x8 pa = {(__bf16)e[0][0], (__bf16)e[0][1], (__bf16)e[0][2], (__bf16)e[0][3],
                         (__bf16)e[1][0], (__bf16)e[1][1], (__bf16)e[1][2], (__bf16)e[1][3]};
      const int inr0 = (64 * kg + 8 * g) ^ kswz;
      const int inr1 = (64 * kg + 32 + 8 * g) ^ kswz;
#pragma unroll
      for (int dt = 0; dt < 4; ++dt) {
        const char* vrow = smem + 16384 + coff + (dt * 16 + ci) * 256;
        const bf16x4 v0 = *(const bf16x4*)(vrow + inr0);
        const bf16x4 v1 = *(const bf16x4*)(vrow + inr1);
        const bf16x8 vb = {v0[0], v0[1], v0[2], v0[3], v1[0], v1[1], v1[2], v1[3]};
        apv[dt] = mfma16(pa, vb, apv[dt]);
      }
      FENCE_LGKM0();
    }

    // ---- transition: Cb write for tile i, linv for tile i+1 ----
    __syncthreads();               // all tile reads done -> pvf may overwrite slots
    {
      const int basew = (qg * 4 + kg) * 16;
#pragma unroll
      for (int dt = 0; dt < 4; ++dt)
#pragma unroll
        for (int r = 0; r < 4; ++r)
          pvf[(basew + 4 * g + r) * 68 + dt * 16 + ci] = apv[dt][r];
    }
    if (more) {
      nrs += __shfl_xor(nrs, 16);
      nrs += __shfl_xor(nrs, 32);
      if (lane < 16) rs_lds[w][lane] = nrs;
    }
    __syncthreads();
    {
      const int qq  = tid >> 4;
      const int d0  = (tid & 15) * 4;
      const int qg2 = qq >> 4, row = qq & 15;
      f32x4 ss = {0.f, 0.f, 0.f, 0.f};
#pragma unroll
      for (int kk = 0; kk < 4; ++kk)
        ss += *(const f32x4*)&pvf[((qg2 * 4 + kk) * 16 + row) * 68 + d0];
      const int b = bh >> 4, h = bh & 15;
      const int srow = (qgrp * GQT + i) * QBLK + qq;
      const bf16x4 o = {(__bf16)ss[0], (__bf16)ss[1], (__bf16)ss[2], (__bf16)ss[3]};
      *(bf16x4*)&Cbuf[((size_t)b * SEQ + srow) * FEA + h * 64 + d0] = o;
    }
    if (more && tid < QBLK) {
      const int qg2 = tid >> 4;
      float ts = 0.f;
#pragma unroll
      for (int kk = 0; kk < 4; ++kk) ts += rs_lds[qg2 * 4 + kk][tid & 15];
      linv_lds[tid] = -__log2f(ts);
    }
    cq0 = nq0; cq1 = nq1;
    FENCE_LGKM0();                 // pvf reads retired before next STAGE overwrites
    __syncthreads();
  }
#undef STAGE_K
#undef STAGE_V
}

// ------------------------------------------------------------------ launch ---
extern "C" void kernel_launch(void* const* d_in, const int* in_sizes, int n_in,
                              void* d_out, int out_size, void* d_ws, size_t ws_size,
                              hipStream_t stream) {
  const float* q    = (const float*)d_in[0];
  const float* k    = (const float*)d_in[1];
  const float* v    = (const float*)d_in[2];
  const float* wq_w = (const float*)d_in[3];
  const float* wq_b = (const float*)d_in[4];
  const float* wk_w = (const float*)d_in[5];
  const float* wk_b = (const float*)d_in[6];
  const float* wv_w = (const float*)d_in[7];
  const float* wv_b = (const float*)d_in[8];
  const float* fc_w = (const float*)d_in[9];
  const float* fc_b = (const float*)d_in[10];

  float* out0 = (float*)d_out;
  float* attn = out0 + (size_t)MROWS * FEA;  // second tuple output

  // bf16 scratch that dies before attn runs -> reuse the attn output region
  __bf16* Xq = (__bf16*)attn;
  __bf16* Xk = Xq + (size_t)MROWS * FEA;
  __bf16* Xv = Xk + (size_t)MROWS * FEA;
  __bf16* Wq = Xv + (size_t)MROWS * FEA;
  __bf16* Wk = Wq + (size_t)FEA * FEA;
  __bf16* Wv = Wk + (size_t)FEA * FEA;

  // persistent scratch (lives across attn) -> d_ws, 34 MiB
  __bf16* Qh  = (__bf16*)d_ws;
  __bf16* Kh  = Qh  + (size_t)MROWS * FEA;
  __bf16* VhT = Kh  + (size_t)MROWS * FEA;
  __bf16* Cb  = VhT + (size_t)MROWS * FEA;
  __bf16* Wfc = Cb  + (size_t)MROWS * FEA;

  ConvArgs ca;
  ca.seg[0] = {q,    Xq,  (MROWS * FEA) / 4, 1.0f};
  ca.seg[1] = {k,    Xk,  (MROWS * FEA) / 4, 1.0f};
  ca.seg[2] = {v,    Xv,  (MROWS * FEA) / 4, 1.0f};
  ca.seg[3] = {wq_w, Wq,  (FEA * FEA) / 4,   QK_SCALE};
  ca.seg[4] = {wk_w, Wk,  (FEA * FEA) / 4,   1.0f};
  ca.seg[5] = {wv_w, Wv,  (FEA * FEA) / 4,   1.0f};
  ca.seg[6] = {fc_w, Wfc, (FEA * FEA) / 4,   1.0f};
  convert_k<<<dim3(512, 7), 256, 0, stream>>>(ca);

  QkvArgs qa;
  qa.A[0] = Xq; qa.Bt[0] = Wq; qa.bias[0] = wq_b; qa.bscale[0] = QK_SCALE; qa.out[0] = Qh;
  qa.A[1] = Xk; qa.Bt[1] = Wk; qa.bias[1] = wk_b; qa.bscale[1] = 1.0f;     qa.out[1] = Kh;
  qa.A[2] = Xv; qa.Bt[2] = Wv; qa.bias[2] = wv_b; qa.bscale[2] = 1.0f;     qa.out[2] = VhT;
  gemm_qkv<<<dim3(MROWS / 128, FEA / 128, 3), 256, 0, stream>>>(qa);

  attn_fused<<<dim3(512), 512, 0, stream>>>(Qh, Kh, VhT, attn, Cb);

  gemm_fc<<<dim3(MROWS / 128, FEA / 128), 256, 0, stream>>>(Cb, Wfc, fc_b, out0);
}

// Round 13
// 216.264 us; speedup vs baseline: 2.5719x; 1.1092x over previous
//
#include <hip/hip_runtime.h>
#include <stdint.h>

#define DEV __device__ __forceinline__

using f32x4  = __attribute__((ext_vector_type(4))) float;
using bf16x8 = __attribute__((ext_vector_type(8))) __bf16;
using bf16x4 = __attribute__((ext_vector_type(4))) __bf16;

static constexpr int SEQ  = 2048;
static constexpr int FEA  = 1024;
static constexpr int NHEAD = 16;
static constexpr int MROWS = 4096;  // B*S
// scale folded into Wq: (1/sqrt(64)) * log2(e)  -> scores directly in exp2 domain
static constexpr float QK_SCALE = 0.18033688011112042f;

DEV f32x4 mfma16(bf16x8 a, bf16x8 b, f32x4 c) {
  return __builtin_amdgcn_mfma_f32_16x16x32_bf16(a, b, c, 0, 0, 0);
}

DEV void gload16(const void* g, void* l) {
  __builtin_amdgcn_global_load_lds((__attribute__((address_space(1))) void*)g,
                                   (__attribute__((address_space(3))) void*)l,
                                   16, 0, 0);
}

#define FENCE_VMCNT(n) asm volatile("s_waitcnt vmcnt(" #n ")" ::: "memory")
#define FENCE_LGKM0()  asm volatile("s_waitcnt lgkmcnt(0)" ::: "memory")

// ---------------------------------------------------------------- convert ---
struct ConvSeg { const float* src; __bf16* dst; int n4; float scale; };
struct ConvArgs { ConvSeg seg[7]; };

__global__ __launch_bounds__(256) void convert_k(ConvArgs a) {
  const ConvSeg sg = a.seg[blockIdx.y];
  const int stride = gridDim.x * blockDim.x;
  for (int i = blockIdx.x * blockDim.x + threadIdx.x; i < sg.n4; i += stride) {
    const f32x4 v = *(const f32x4*)(sg.src + (size_t)i * 4);
    bf16x4 o = {(__bf16)(v[0] * sg.scale), (__bf16)(v[1] * sg.scale),
                (__bf16)(v[2] * sg.scale), (__bf16)(v[3] * sg.scale)};
    *(bf16x4*)(sg.dst + (size_t)i * 4) = o;
  }
}

// ------------------------------------------------------------------- GEMM ---
DEV void gemm_core64(const __bf16* __restrict__ A, const __bf16* __restrict__ Bt,
                     char* lds, int row0, int col0, int tid, f32x4 (&acc)[4][4]) {
  char* Alds = lds;
  char* Blds = lds + 16384;
  constexpr int K = 1024;
  const int lane = tid & 63;
  const int w    = tid >> 6;
  const int ci   = lane & 15;
  const int g    = lane >> 4;
  const int wr   = w >> 1, wc = w & 1;

  const __bf16* gA[4]; const __bf16* gB[4];
  char* lA[4]; char* lB[4];
#pragma unroll
  for (int j = 0; j < 4; ++j) {
    const int c = tid + 256 * j;
    const int r = c >> 3, s = c & 7;
    const int gsw = (s ^ (r & 7)) * 8;     // pre-swizzled source column
    gA[j] = A  + (size_t)(row0 + r) * K + gsw;
    gB[j] = Bt + (size_t)(col0 + r) * K + gsw;
    lA[j] = Alds + c * 16;
    lB[j] = Blds + c * 16;
  }
  const int rsw = (ci & 7) << 4;

  for (int k0 = 0; k0 < K; k0 += 64) {
    __syncthreads();
#pragma unroll
    for (int j = 0; j < 4; ++j) {
      gload16(gA[j] + k0, lA[j]);
      gload16(gB[j] + k0, lB[j]);
    }
    __syncthreads();
#pragma unroll
    for (int kk = 0; kk < 2; ++kk) {
      bf16x8 af[4], bfr[4];
#pragma unroll
      for (int m = 0; m < 4; ++m)
        af[m] = *(const bf16x8*)(Alds + (wr * 64 + m * 16 + ci) * 128 +
                                 ((kk * 64 + g * 16) ^ rsw));
#pragma unroll
      for (int n = 0; n < 4; ++n)
        bfr[n] = *(const bf16x8*)(Blds + (wc * 64 + n * 16 + ci) * 128 +
                                  ((kk * 64 + g * 16) ^ rsw));
#pragma unroll
      for (int m = 0; m < 4; ++m)
#pragma unroll
        for (int n = 0; n < 4; ++n)
          acc[m][n] = mfma16(af[m], bfr[n], acc[m][n]);
    }
  }
}

struct QkvArgs {
  const __bf16* A[3];
  const __bf16* Bt[3];
  const float*  bias[3];
  float         bscale[3];
  __bf16*       out[3];
};

__global__ __launch_bounds__(256) void gemm_qkv(QkvArgs args) {
  __shared__ __align__(16) char lds[32768];
  const int z = blockIdx.z;
  const int tid = threadIdx.x;
  const int row0 = blockIdx.x * 128;
  const int col0 = blockIdx.y * 128;
  f32x4 acc[4][4] = {};
  gemm_core64(args.A[z], args.Bt[z], lds, row0, col0, tid, acc);

  const int lane = tid & 63;
  const int ci = lane & 15, g = lane >> 4;
  const int w = tid >> 6;
  const int wr = w >> 1, wc = w & 1;
  const float* bias = args.bias[z];
  const float bscale = args.bscale[z];
  __bf16* outp = args.out[z];
  const bool vt = (z == 2);
#pragma unroll
  for (int m = 0; m < 4; ++m)
#pragma unroll
    for (int n = 0; n < 4; ++n)
#pragma unroll
      for (int r = 0; r < 4; ++r) {
        const int gr = row0 + wr * 64 + m * 16 + 4 * g + r;
        const int gc = col0 + wc * 64 + n * 16 + ci;
        const float vv = acc[m][n][r] + bias[gc] * bscale;
        const int b = gr >> 11, s = gr & (SEQ - 1);
        const int h = gc >> 6,  d = gc & 63;
        if (!vt)
          outp[(((size_t)b * NHEAD + h) * SEQ + s) * 64 + d] = (__bf16)vv;
        else
          outp[(((size_t)b * NHEAD + h) * 64 + d) * SEQ + s] = (__bf16)vv;
      }
}

__global__ __launch_bounds__(256) void gemm_fc(const __bf16* __restrict__ A,
                                               const __bf16* __restrict__ Bt,
                                               const float* __restrict__ bias,
                                               float* __restrict__ outp) {
  __shared__ __align__(16) char lds[32768];
  const int tid = threadIdx.x;
  const int row0 = blockIdx.x * 128;
  const int col0 = blockIdx.y * 128;
  f32x4 acc[4][4] = {};
  gemm_core64(A, Bt, lds, row0, col0, tid, acc);

  const int lane = tid & 63;
  const int ci = lane & 15, g = lane >> 4;
  const int w = tid >> 6;
  const int wr = w >> 1, wc = w & 1;
#pragma unroll
  for (int m = 0; m < 4; ++m)
#pragma unroll
    for (int n = 0; n < 4; ++n)
#pragma unroll
      for (int r = 0; r < 4; ++r) {
        const int gr = row0 + wr * 64 + m * 16 + 4 * g + r;
        const int gc = col0 + wc * 64 + n * 16 + ci;
        const float vv = fmaxf(acc[m][n][r] + bias[gc], 0.0f);
        __builtin_nontemporal_store(vv, &outp[(size_t)gr * FEA + gc]);
      }
}

// -------------------------------------------------------------- attention ---
// R9 structure restored (nt stores — R12 measured plain stores +16us worse);
// pvf reduce stride 68 f32 at smem BASE (34.8KB, fits; race-free: writes after
// post-loop barrier, reads before loop-final barrier, next STAGE after that);
// T5 s_setprio(1) around each tile's MFMA+exp cluster (attn-positive, m191).
static constexpr int QBLK = 32;
static constexpr int GQT  = 4;           // q-tiles per block
static constexpr int KVB  = 128;
static constexpr int NT   = SEQ / KVB;   // 16

__global__ __launch_bounds__(512, 4) void attn_fused(const __bf16* __restrict__ Qh,
                                                     const __bf16* __restrict__ Kh,
                                                     const __bf16* __restrict__ VhT,
                                                     float* __restrict__ attn_out,
                                                     __bf16* __restrict__ Cbuf) {
  __shared__ __align__(16) char smem[65536];
  __shared__ float rs_lds[8][16];
  __shared__ float linv_lds[QBLK];
  float* pvf = (float*)smem;             // 128 x 68 f32 = 34.8KB at base

  const int tid  = threadIdx.x;
  const int lane = tid & 63;
  const int w    = tid >> 6;
  const int ci   = lane & 15;
  const int g    = lane >> 4;
  const int qg   = w >> 2;
  const int kg   = w & 3;

  const int id   = blockIdx.x;           // 512 blocks
  const int xcd  = id & 7;
  const int idx  = id >> 3;              // 0..63
  const int bh   = xcd * 4 + (idx >> 4);
  const int qgrp = idx & 15;

  const __bf16* Qbase = Qh + ((size_t)bh * SEQ + (size_t)qgrp * (QBLK * GQT)) * 64;
  const char*   Kbyt  = (const char*)(Kh  + (size_t)bh * SEQ * 64);
  const char*   Vbyt  = (const char*)(VhT + (size_t)bh * 64 * SEQ);

  const int cA = tid, cB = tid + 512;
  const int kgoffA = ((cA >> 3) * 128) + (((cA & 7) ^ ((cA >> 3) & 7)) * 16);
  const int kgoffB = ((cB >> 3) * 128) + (((cB & 7) ^ ((cB >> 3) & 7)) * 16);
  const int vdA = cA >> 4, vdB = cB >> 4;
  const int vgoffA = vdA * (SEQ * 2) + (((cA & 15) ^ (vdA & 7)) * 16);
  const int vgoffB = vdB * (SEQ * 2) + (((cB & 15) ^ (vdB & 7)) * 16);

#define STAGE_K(t, boff) { gload16(Kbyt + (size_t)(t) * 16384 + kgoffA, smem + (boff) + cA * 16); \
                           gload16(Kbyt + (size_t)(t) * 16384 + kgoffB, smem + (boff) + cB * 16); }
#define STAGE_V(t, boff) { gload16(Vbyt + (size_t)(t) * 256 + vgoffA, smem + 16384 + (boff) + cA * 16); \
                           gload16(Vbyt + (size_t)(t) * 256 + vgoffB, smem + 16384 + (boff) + cB * 16); }

  const int kswz  = (ci & 7) << 4;
  const int krow0 = kg * 4096 + ci * 128;

  // current q-tile fragments (tile 0)
  bf16x8 cq0, cq1;
  {
    const __bf16* qp = Qbase + (qg * 16 + ci) * 64;
    cq0 = *(const bf16x8*)(qp + 8 * g);
    cq1 = *(const bf16x8*)(qp + 32 + 8 * g);
  }

  // ---- prologue: rowsums for q-tile 0 ----
  float rs = 0.f;
  STAGE_K(0, 0);
  STAGE_K(1, 16384);
  for (int p = 0; p < NT / 2; ++p) {
    const int base = (p & 1) << 15;
    __builtin_amdgcn_s_barrier();
    if (p < NT / 2 - 1) {
      STAGE_K(2 * p + 2, base ^ 32768);
      STAGE_K(2 * p + 3, (base ^ 32768) + 16384);
      FENCE_VMCNT(4);
    } else {
      FENCE_VMCNT(0);
    }
    __builtin_amdgcn_s_setprio(1);
#pragma unroll
    for (int hb = 0; hb < 2; ++hb) {
      const char* kt = smem + base + hb * 16384 + krow0;
#pragma unroll
      for (int s = 0; s < 2; ++s) {
        const bf16x8 k0 = *(const bf16x8*)(kt + s * 2048 + ((16 * g) ^ kswz));
        const bf16x8 k1 = *(const bf16x8*)(kt + s * 2048 + ((64 + 16 * g) ^ kswz));
        f32x4 sf = {0.f, 0.f, 0.f, 0.f};
        sf = mfma16(k0, cq0, sf);
        sf = mfma16(k1, cq1, sf);
#pragma unroll
        for (int r = 0; r < 4; ++r) rs += __builtin_amdgcn_exp2f(sf[r]);
      }
    }
    __builtin_amdgcn_s_setprio(0);
    FENCE_LGKM0();
  }
  rs += __shfl_xor(rs, 16);
  rs += __shfl_xor(rs, 32);
  if (lane < 16) rs_lds[w][lane] = rs;
  __syncthreads();
  if (tid < QBLK) {
    const int qg2 = tid >> 4;
    float ts = 0.f;
#pragma unroll
    for (int kk = 0; kk < 4; ++kk) ts += rs_lds[qg2 * 4 + kk][tid & 15];
    linv_lds[tid] = -__log2f(ts);
  }
  __syncthreads();

  // ---- main: merged pass2(i) + pass1(i+1) ----
  for (int i = 0; i < GQT; ++i) {
    const bool more = (i + 1 < GQT);
    bf16x8 nq0 = {}, nq1 = {};
    if (more) {
      const __bf16* qp = Qbase + ((i + 1) * QBLK + qg * 16 + ci) * 64;
      nq0 = *(const bf16x8*)(qp + 8 * g);
      nq1 = *(const bf16x8*)(qp + 32 + 8 * g);
    }
    const float linv = linv_lds[qg * 16 + ci];
    float* orow = attn_out + ((size_t)bh * SEQ + (size_t)(qgrp * GQT + i) * QBLK +
                              qg * 16 + ci) * SEQ + kg * 32 + 4 * g;
    f32x4 apv[4] = {};
    float nrs = 0.f;

    STAGE_K(0, 0);
    STAGE_V(0, 0);
    for (int t = 0; t < NT; ++t) {
      const int coff = (t & 1) << 15;
      __builtin_amdgcn_s_barrier();
      if (t < NT - 1) {
        STAGE_K(t + 1, coff ^ 32768);
        STAGE_V(t + 1, coff ^ 32768);
        if (t == 0) FENCE_VMCNT(4);
        else        FENCE_VMCNT(6);
      } else {
        FENCE_VMCNT(2);
      }

      __builtin_amdgcn_s_setprio(1);
      f32x4 e[2];
#pragma unroll
      for (int s = 0; s < 2; ++s) {
        const char* kt = smem + coff + krow0 + s * 2048;
        const bf16x8 k0 = *(const bf16x8*)(kt + ((16 * g) ^ kswz));
        const bf16x8 k1 = *(const bf16x8*)(kt + ((64 + 16 * g) ^ kswz));
        f32x4 sf = {0.f, 0.f, 0.f, 0.f};
        sf = mfma16(k0, cq0, sf);
        sf = mfma16(k1, cq1, sf);
        if (more) {
          f32x4 nsf = {0.f, 0.f, 0.f, 0.f};
          nsf = mfma16(k0, nq0, nsf);
          nsf = mfma16(k1, nq1, nsf);
#pragma unroll
          for (int r = 0; r < 4; ++r) nrs += __builtin_amdgcn_exp2f(nsf[r]);
        }
#pragma unroll
        for (int r = 0; r < 4; ++r) e[s][r] = __builtin_amdgcn_exp2f(sf[r] + linv);
      }
      // both nt stores back-to-back (adjacent in the VMEM stream)
      __builtin_nontemporal_store(e[0], (f32x4*)(orow + t * 128));
      __builtin_nontemporal_store(e[1], (f32x4*)(orow + t * 128 + 16));

      const bf16x8 pa = {(__bf16)e[0][0], (__bf16)e[0][1], (__bf16)e[0][2], (__bf16)e[0][3],
                         (__bf16)e[1][0], (__bf16)e[1][1], (__bf16)e[1][2], (__bf16)e[1][3]};
      const int inr0 = (64 * kg + 8 * g) ^ kswz;
      const int inr1 = (64 * kg + 32 + 8 * g) ^ kswz;
#pragma unroll
      for (int dt = 0; dt < 4; ++dt) {
        const char* vrow = smem + 16384 + coff + (dt * 16 + ci) * 256;
        const bf16x4 v0 = *(const bf16x4*)(vrow + inr0);
        const bf16x4 v1 = *(const bf16x4*)(vrow + inr1);
        const bf16x8 vb = {v0[0], v0[1], v0[2], v0[3], v1[0], v1[1], v1[2], v1[3]};
        apv[dt] = mfma16(pa, vb, apv[dt]);
      }
      __builtin_amdgcn_s_setprio(0);
      FENCE_LGKM0();
    }

    // ---- transition: Cb write for tile i, linv for tile i+1 ----
    __syncthreads();               // all tile reads done -> pvf may overwrite slots
    {
      const int basew = (qg * 4 + kg) * 16;
#pragma unroll
      for (int dt = 0; dt < 4; ++dt)
#pragma unroll
        for (int r = 0; r < 4; ++r)
          pvf[(basew + 4 * g + r) * 68 + dt * 16 + ci] = apv[dt][r];
    }
    if (more) {
      nrs += __shfl_xor(nrs, 16);
      nrs += __shfl_xor(nrs, 32);
      if (lane < 16) rs_lds[w][lane] = nrs;
    }
    __syncthreads();
    {
      const int qq  = tid >> 4;
      const int d0  = (tid & 15) * 4;
      const int qg2 = qq >> 4, row = qq & 15;
      f32x4 ss = {0.f, 0.f, 0.f, 0.f};
#pragma unroll
      for (int kk = 0; kk < 4; ++kk)
        ss += *(const f32x4*)&pvf[((qg2 * 4 + kk) * 16 + row) * 68 + d0];
      const int b = bh >> 4, h = bh & 15;
      const int srow = (qgrp * GQT + i) * QBLK + qq;
      const bf16x4 o = {(__bf16)ss[0], (__bf16)ss[1], (__bf16)ss[2], (__bf16)ss[3]};
      *(bf16x4*)&Cbuf[((size_t)b * SEQ + srow) * FEA + h * 64 + d0] = o;
    }
    if (more && tid < QBLK) {
      const int qg2 = tid >> 4;
      float ts = 0.f;
#pragma unroll
      for (int kk = 0; kk < 4; ++kk) ts += rs_lds[qg2 * 4 + kk][tid & 15];
      linv_lds[tid] = -__log2f(ts);
    }
    cq0 = nq0; cq1 = nq1;
    FENCE_LGKM0();                 // pvf reads retired before next STAGE overwrites
    __syncthreads();
  }
#undef STAGE_K
#undef STAGE_V
}

// ------------------------------------------------------------------ launch ---
extern "C" void kernel_launch(void* const* d_in, const int* in_sizes, int n_in,
                              void* d_out, int out_size, void* d_ws, size_t ws_size,
                              hipStream_t stream) {
  const float* q    = (const float*)d_in[0];
  const float* k    = (const float*)d_in[1];
  const float* v    = (const float*)d_in[2];
  const float* wq_w = (const float*)d_in[3];
  const float* wq_b = (const float*)d_in[4];
  const float* wk_w = (const float*)d_in[5];
  const float* wk_b = (const float*)d_in[6];
  const float* wv_w = (const float*)d_in[7];
  const float* wv_b = (const float*)d_in[8];
  const float* fc_w = (const float*)d_in[9];
  const float* fc_b = (const float*)d_in[10];

  float* out0 = (float*)d_out;
  float* attn = out0 + (size_t)MROWS * FEA;  // second tuple output

  // bf16 scratch that dies before attn runs -> reuse the attn output region
  __bf16* Xq = (__bf16*)attn;
  __bf16* Xk = Xq + (size_t)MROWS * FEA;
  __bf16* Xv = Xk + (size_t)MROWS * FEA;
  __bf16* Wq = Xv + (size_t)MROWS * FEA;
  __bf16* Wk = Wq + (size_t)FEA * FEA;
  __bf16* Wv = Wk + (size_t)FEA * FEA;

  // persistent scratch (lives across attn) -> d_ws, 34 MiB
  __bf16* Qh  = (__bf16*)d_ws;
  __bf16* Kh  = Qh  + (size_t)MROWS * FEA;
  __bf16* VhT = Kh  + (size_t)MROWS * FEA;
  __bf16* Cb  = VhT + (size_t)MROWS * FEA;
  __bf16* Wfc = Cb  + (size_t)MROWS * FEA;

  ConvArgs ca;
  ca.seg[0] = {q,    Xq,  (MROWS * FEA) / 4, 1.0f};
  ca.seg[1] = {k,    Xk,  (MROWS * FEA) / 4, 1.0f};
  ca.seg[2] = {v,    Xv,  (MROWS * FEA) / 4, 1.0f};
  ca.seg[3] = {wq_w, Wq,  (FEA * FEA) / 4,   QK_SCALE};
  ca.seg[4] = {wk_w, Wk,  (FEA * FEA) / 4,   1.0f};
  ca.seg[5] = {wv_w, Wv,  (FEA * FEA) / 4,   1.0f};
  ca.seg[6] = {fc_w, Wfc, (FEA * FEA) / 4,   1.0f};
  convert_k<<<dim3(512, 7), 256, 0, stream>>>(ca);

  QkvArgs qa;
  qa.A[0] = Xq; qa.Bt[0] = Wq; qa.bias[0] = wq_b; qa.bscale[0] = QK_SCALE; qa.out[0] = Qh;
  qa.A[1] = Xk; qa.Bt[1] = Wk; qa.bias[1] = wk_b; qa.bscale[1] = 1.0f;     qa.out[1] = Kh;
  qa.A[2] = Xv; qa.Bt[2] = Wv; qa.bias[2] = wv_b; qa.bscale[2] = 1.0f;     qa.out[2] = VhT;
  gemm_qkv<<<dim3(MROWS / 128, FEA / 128, 3), 256, 0, stream>>>(qa);

  attn_fused<<<dim3(512), 512, 0, stream>>>(Qh, Kh, VhT, attn, Cb);

  gemm_fc<<<dim3(MROWS / 128, FEA / 128), 256, 0, stream>>>(Cb, Wfc, fc_b, out0);
}